// Round 6
// baseline (53.129 us; speedup 1.0000x reference)
//
#include <hip/hip_runtime.h>
#include <hip/hip_bf16.h>

// PositionEmbeddingSine, fused + pair-grouped: out[b,c,h,w], c in [0,256).
//   c <  128: k=c,     embed = y_embed[b,h,w]   (cumsum of !mask along H, norm'd)
//   c >= 128: k=c-128, embed = x_embed[b,h,w]   (cumsum of !mask along W, norm'd)
//   val = (k even) ? sin(embed*inv_dim_t[k]) : cos(embed*inv_dim_t[k])
//   inv_dim_t[k] = 10000^(-2*(k/2)/128); pair (2j,2j+1) shares the angle.
// Grid = 1024 blocks (exactly 4/CU, whole grid co-resident). Each block:
//   build its batch's embed plane in LDS ONCE, then emit FOUR channel-pairs
//   (8 output planes, one contiguous 288 KB region). Setup cost amortized 4x
//   and fully parallel at kernel start; rest is a pure store stream.

#define BATCH 32
#define HH 96
#define WW 96
#define CC 256
#define F_HALF 128
#define PLANE   (HH * WW)        // 9216
#define PLANE4  (PLANE / 4)      // 2304
#define ITERS   (PLANE4 / 256)   // 9
#define PITCH   100              // LDS row pitch (floats): 400 B, 16B-aligned,
                                 // breaks pitch-96's 64-way bank conflict

#define LOG2_TEMP 13.287712379549449f   // log2(10000)
#define TWO_PI 6.2831853071795864769f

typedef float f32x4 __attribute__((ext_vector_type(4)));

__global__ void __launch_bounds__(256)
pes_fused_kernel(const unsigned char* __restrict__ mask,
                 float* __restrict__ out) {
    __shared__ float emb[HH * PITCH];   // 37.5 KB -> 4 blocks/CU

    // p in [0,1024): b = batch, half = y/x, g = group of 4 pairs
    int p = blockIdx.x;
    int b    = p >> 5;          // / 32
    int r    = p & 31;
    int half = r >> 4;          // 0: y-embed (c<128), 1: x-embed (c>=128)
    int g    = r & 15;          // 4 pairs: jj = 4g..4g+3

    const unsigned char* mb = mask + (size_t)b * PLANE;
    int t = threadIdx.x;
    const float eps = 1e-6f;

    // ---- build the embed plane in LDS (96 threads, rest wait) ----
    if (half == 0) {
        // y_embed: cumsum along H at fixed column w = t; coalesced byte loads.
        if (t < WW) {
            int w = t;
            float s = 0.f;
            for (int h = 0; h < HH; ++h) s += (mb[h * WW + w] == 0) ? 1.f : 0.f;
            float f = TWO_PI / (s + eps);
            float cum = 0.f;
            for (int h = 0; h < HH; ++h) {
                cum += (mb[h * WW + w] == 0) ? 1.f : 0.f;
                emb[h * PITCH + w] = cum * f;   // bank (25h*4+w)%32: spread
            }
        }
    } else {
        // x_embed: cumsum along W at fixed row h = t (serial per thread).
        if (t < HH) {
            int h = t;
            const unsigned char* mr = mb + h * WW;
            float s = 0.f;
            for (int w = 0; w < WW; ++w) s += (mr[w] == 0) ? 1.f : 0.f;
            float f = TWO_PI / (s + eps);
            float cum = 0.f;
            for (int w = 0; w < WW; ++w) {
                cum += (mr[w] == 0) ? 1.f : 0.f;
                emb[h * PITCH + w] = cum * f;   // 8-way conflict, ~once total
            }
        }
    }
    __syncthreads();

    // ---- per-pair scale factors (uniform across block) ----
    float inv0 = exp2f((float)(4 * g + 0) * (-2.0f / (float)F_HALF) * LOG2_TEMP);
    float inv1 = exp2f((float)(4 * g + 1) * (-2.0f / (float)F_HALF) * LOG2_TEMP);
    float inv2 = exp2f((float)(4 * g + 2) * (-2.0f / (float)F_HALF) * LOG2_TEMP);
    float inv3 = exp2f((float)(4 * g + 3) * (-2.0f / (float)F_HALF) * LOG2_TEMP);

    // output: 8 contiguous planes starting at channel 128*half + 8g
    float* ob = out + ((size_t)b * CC + 128 * half + 8 * g) * PLANE;
    f32x4* op0 = (f32x4*)ob;             // pair0 sin
    // pair q sin plane = op0 + 2q*PLANE4, cos plane = +PLANE4 more

#pragma unroll
    for (int it = 0; it < ITERS; ++it) {
        int idx = t + it * 256;          // f32x4 index within a plane
        int h = idx / 24;                // 24 f32x4 per row
        int k = idx - h * 24;
        f32x4 e = *(const f32x4*)&emb[h * PITCH + 4 * k];

#define EMIT(q, invq)                                                        \
        {                                                                    \
            f32x4 a, rs, rc;                                                 \
            a.x = e.x * invq; a.y = e.y * invq;                              \
            a.z = e.z * invq; a.w = e.w * invq;                              \
            rs.x = __sinf(a.x); rs.y = __sinf(a.y);                          \
            rs.z = __sinf(a.z); rs.w = __sinf(a.w);                          \
            rc.x = __cosf(a.x); rc.y = __cosf(a.y);                          \
            rc.z = __cosf(a.z); rc.w = __cosf(a.w);                          \
            op0[(size_t)(2 * q) * PLANE4 + idx] = rs;                        \
            op0[(size_t)(2 * q + 1) * PLANE4 + idx] = rc;                    \
        }
        EMIT(0, inv0)
        EMIT(1, inv1)
        EMIT(2, inv2)
        EMIT(3, inv3)
#undef EMIT
    }
}

extern "C" void kernel_launch(void* const* d_in, const int* in_sizes, int n_in,
                              void* d_out, int out_size, void* d_ws, size_t ws_size,
                              hipStream_t stream) {
    // inputs: d_in[0] = x (unused, dtype carrier), d_in[1] = mask (bool, 32*96*96)
    const unsigned char* mask = (const unsigned char*)d_in[1];
    float* out = (float*)d_out;

    // single dispatch: 32 batches x 2 halves x 16 pair-groups = 1024 blocks
    pes_fused_kernel<<<BATCH * 2 * 16, 256, 0, stream>>>(mask, out);
}

// Round 7
// 52.577 us; speedup vs baseline: 1.0105x; 1.0105x over previous
//
#include <hip/hip_runtime.h>
#include <hip/hip_bf16.h>

// PositionEmbeddingSine, fused, channel-major stores: out[b,c,h,w], c in [0,256).
//   c <  128: k=c,     embed = y_embed[b,h,w]   (cumsum of !mask along H, norm'd)
//   c >= 128: k=c-128, embed = x_embed[b,h,w]   (cumsum of !mask along W, norm'd)
//   val = (k even) ? sin(embed*inv_dim_t[k]) : cos(embed*inv_dim_t[k])
//   inv_dim_t[k] = 10000^(-2*(k/2)/128)
// Grid = 1024 blocks (exactly 4/CU, fully co-resident). Each block: build its
// batch's embed plane in LDS once, then write 8 consecutive channel planes
// ONE AT A TIME -> a single monotone 288 KB store stream per block (the same
// temporal pattern as the 7 TB/s fill kernels), instead of 8 interleaved
// streams 36 KB apart.

#define BATCH 32
#define HH 96
#define WW 96
#define CC 256
#define F_HALF 128
#define PLANE   (HH * WW)        // 9216
#define PLANE4  (PLANE / 4)      // 2304
#define ITERS   (PLANE4 / 256)   // 9
#define PITCH   100              // LDS row pitch (floats): 400 B, 16B-aligned

#define LOG2_TEMP 13.287712379549449f   // log2(10000)
#define TWO_PI 6.2831853071795864769f

typedef float f32x4 __attribute__((ext_vector_type(4)));

__global__ void __launch_bounds__(256)
pes_fused_kernel(const unsigned char* __restrict__ mask,
                 float* __restrict__ out) {
    __shared__ float emb[HH * PITCH];   // 37.5 KB -> 4 blocks/CU

    // p in [0,1024): b = batch, half = y/x, g = group of 8 channels
    int p = blockIdx.x;
    int b    = p >> 5;          // / 32
    int r    = p & 31;
    int half = r >> 4;          // 0: y-embed (c<128), 1: x-embed (c>=128)
    int g    = r & 15;          // channels within half: 8g .. 8g+7

    const unsigned char* mb = mask + (size_t)b * PLANE;
    int t = threadIdx.x;
    const float eps = 1e-6f;

    // ---- build the embed plane in LDS (96 threads, rest wait) ----
    if (half == 0) {
        // y_embed: cumsum along H at fixed column w = t; coalesced byte loads.
        if (t < WW) {
            int w = t;
            float s = 0.f;
            for (int h = 0; h < HH; ++h) s += (mb[h * WW + w] == 0) ? 1.f : 0.f;
            float f = TWO_PI / (s + eps);
            float cum = 0.f;
            for (int h = 0; h < HH; ++h) {
                cum += (mb[h * WW + w] == 0) ? 1.f : 0.f;
                emb[h * PITCH + w] = cum * f;
            }
        }
    } else {
        // x_embed: cumsum along W at fixed row h = t (serial per thread).
        if (t < HH) {
            int h = t;
            const unsigned char* mr = mb + h * WW;
            float s = 0.f;
            for (int w = 0; w < WW; ++w) s += (mr[w] == 0) ? 1.f : 0.f;
            float f = TWO_PI / (s + eps);
            float cum = 0.f;
            for (int w = 0; w < WW; ++w) {
                cum += (mr[w] == 0) ? 1.f : 0.f;
                emb[h * PITCH + w] = cum * f;
            }
        }
    }
    __syncthreads();

    // ---- 8 channels, one sequential 36 KB plane stream each ----
    // k (freq index within half) = 8g + c8; jj = k>>1; even k -> sin.
    f32x4* ob = (f32x4*)(out + ((size_t)b * CC + 128 * half + 8 * g) * PLANE);

#pragma unroll
    for (int c8 = 0; c8 < 8; ++c8) {
        int k = 8 * g + c8;
        float inv = exp2f((float)(k >> 1) * (-2.0f / (float)F_HALF) * LOG2_TEMP);
        bool use_sin = (k & 1) == 0;          // uniform across block
        f32x4* op = ob + (size_t)c8 * PLANE4;

#pragma unroll
        for (int it = 0; it < ITERS; ++it) {
            int idx = t + it * 256;          // f32x4 index within the plane
            int h = idx / 24;                // 24 f32x4 per row
            int kk = idx - h * 24;
            f32x4 e = *(const f32x4*)&emb[h * PITCH + 4 * kk];
            f32x4 a, rv;
            a.x = e.x * inv; a.y = e.y * inv; a.z = e.z * inv; a.w = e.w * inv;
            if (use_sin) {
                rv.x = __sinf(a.x); rv.y = __sinf(a.y);
                rv.z = __sinf(a.z); rv.w = __sinf(a.w);
            } else {
                rv.x = __cosf(a.x); rv.y = __cosf(a.y);
                rv.z = __cosf(a.z); rv.w = __cosf(a.w);
            }
            op[idx] = rv;
        }
    }
}

extern "C" void kernel_launch(void* const* d_in, const int* in_sizes, int n_in,
                              void* d_out, int out_size, void* d_ws, size_t ws_size,
                              hipStream_t stream) {
    // inputs: d_in[0] = x (unused, dtype carrier), d_in[1] = mask (bool, 32*96*96)
    const unsigned char* mask = (const unsigned char*)d_in[1];
    float* out = (float*)d_out;

    // single dispatch: 32 batches x 2 halves x 16 channel-groups = 1024 blocks
    pes_fused_kernel<<<BATCH * 2 * 16, 256, 0, stream>>>(mask, out);
}